// Round 6
// baseline (742.963 us; speedup 1.0000x reference)
//
#include <hip/hip_runtime.h>

#define D 128
#define BN_EPS 1e-5f

typedef __attribute__((ext_vector_type(8))) short short8;   // 8 x bf16 (4 VGPRs)
typedef __attribute__((ext_vector_type(4))) float floatx4;  // MFMA accumulator

__device__ __forceinline__ float bf2f(unsigned short u) {
    unsigned int x = ((unsigned int)u) << 16;
    return __builtin_bit_cast(float, x);
}
__device__ __forceinline__ unsigned short f2bf(float f) {
    unsigned int x = __builtin_bit_cast(unsigned int, f);
    x = x + 0x7FFFu + ((x >> 16) & 1u);  // round-to-nearest-even
    return (unsigned short)(x >> 16);
}

// ---------------------------------------------------------------------------
// hb0 = bf16( sum_f atom_emb[f, x[n,f], :] + z_emb[z[n], :] )
__global__ void node_init_kernel(const int* __restrict__ x, const int* __restrict__ z,
                                 const float* __restrict__ atom_emb,
                                 const float* __restrict__ z_emb,
                                 unsigned short* __restrict__ hb, int N) {
    int gid = blockIdx.x * blockDim.x + threadIdx.x;
    int node = gid >> 5;
    if (node >= N) return;
    int d0 = (gid & 31) * 4;
    float4 acc = *(const float4*)(z_emb + (size_t)z[node] * D + d0);
#pragma unroll
    for (int f = 0; f < 9; ++f) {
        int v = x[node * 9 + f];
        const float4 t = *(const float4*)(atom_emb + (size_t)(f * 119 + v) * D + d0);
        acc.x += t.x; acc.y += t.y; acc.z += t.z; acc.w += t.w;
    }
    ushort4 o;
    o.x = f2bf(acc.x); o.y = f2bf(acc.y); o.z = f2bf(acc.z); o.w = f2bf(acc.w);
    *(ushort4*)(hb + (size_t)node * D + d0) = o;
}

// ---------------------------------------------------------------------------
// Phase A: single sequential pass over edges -> 8 compact per-dst-slice lists
// (SoA: dstL, payL). Per 4096-edge tile: LDS slice-histogram, ONE global
// reservation per slice, then dense appends. payload = src | comb_idx<<17.
__global__ __launch_bounds__(256)
void partition_kernel(const int* __restrict__ ei, const int* __restrict__ ea,
                      int* __restrict__ dstL, int* __restrict__ payL,
                      int* __restrict__ tail, int E, int N, int cap,
                      int ntiles, int nblocks) {
    __shared__ int lcnt[8], lbase[8];
    const int tid = threadIdx.x;
    for (int tile = blockIdx.x; tile < ntiles; tile += nblocks) {
        const int tb = tile * 4096;
        if (tid < 8) lcnt[tid] = 0;
        __syncthreads();
        int mydst[16], mypay[16];
#pragma unroll
        for (int j = 0; j < 16; ++j) {
            int e = tb + j * 256 + tid;
            if (e < E) {
                int dst = ei[E + e];
                int src = ei[e];
                int c = (ea[3 * e] * 6 + ea[3 * e + 1]) * 6 + ea[3 * e + 2];
                mydst[j] = dst;
                mypay[j] = src | (c << 17);
                int s = (int)((8LL * dst) / N);
                atomicAdd(&lcnt[s], 1);
            } else {
                mydst[j] = -1;
            }
        }
        __syncthreads();
        if (tid < 8) {
            lbase[tid] = atomicAdd(&tail[tid], lcnt[tid]);
            lcnt[tid] = 0;
        }
        __syncthreads();
#pragma unroll
        for (int j = 0; j < 16; ++j) {
            if (mydst[j] >= 0) {
                int s = (int)((8LL * mydst[j]) / N);
                int pos = lbase[s] + atomicAdd(&lcnt[s], 1);
                dstL[(size_t)s * cap + pos] = mydst[j];
                payL[(size_t)s * cap + pos] = mypay[j];
            }
        }
        __syncthreads();
    }
}

// ---------------------------------------------------------------------------
// Phase B: in-degree histogram from compact slice lists (no redundant scans;
// counts region for a slice stays in one XCD's L2 if blockIdx%8 ~ XCD).
__global__ void hist2_kernel(const int* __restrict__ dstL, const int* __restrict__ tail,
                             int* __restrict__ counts, int cap, int stride) {
    const int slice = blockIdx.x & 7;
    const int group = blockIdx.x >> 3;
    const int len = tail[slice];
    const int* dl = dstL + (size_t)slice * cap;
    for (int i = group * 256 + threadIdx.x; i < len; i += stride)
        atomicAdd(&counts[dl[i]], 1);
}

// ---------------------------------------------------------------------------
// Parallel exclusive scan of counts[N] -> offsets[N+1], 3 phases.
__global__ void scan_p1_kernel(const int* __restrict__ counts, int* __restrict__ partials, int N) {
    const int tid = threadIdx.x;
    const int base = blockIdx.x * 1024 + tid * 4;
    int4 c = {0, 0, 0, 0};
    if (base + 3 < N) c = *(const int4*)(counts + base);
    else {
        if (base + 0 < N) c.x = counts[base + 0];
        if (base + 1 < N) c.y = counts[base + 1];
        if (base + 2 < N) c.z = counts[base + 2];
        if (base + 3 < N) c.w = counts[base + 3];
    }
    int s = c.x + c.y + c.z + c.w;
#pragma unroll
    for (int off = 32; off > 0; off >>= 1) s += __shfl_xor(s, off, 64);
    __shared__ int ws[4];
    if ((tid & 63) == 0) ws[tid >> 6] = s;
    __syncthreads();
    if (tid == 0) partials[blockIdx.x] = ws[0] + ws[1] + ws[2] + ws[3];
}

__global__ void scan_p2_kernel(int* __restrict__ partials, int nb) {
    const int tid = threadIdx.x;  // 128 threads, nb <= 128
    const int lane = tid & 63, wid = tid >> 6;
    int v = (tid < nb) ? partials[tid] : 0;
    int s = v;
#pragma unroll
    for (int off = 1; off < 64; off <<= 1) {
        int t = __shfl_up(s, off, 64);
        if (lane >= off) s += t;
    }
    __shared__ int ws2[2];
    if (lane == 63) ws2[wid] = s;
    __syncthreads();
    if (wid == 1) s += ws2[0];
    if (tid < nb) partials[tid] = s - v;  // exclusive
}

__global__ void scan_p3_kernel(const int* __restrict__ counts, const int* __restrict__ partials,
                               int* __restrict__ offsets, int N) {
    const int tid = threadIdx.x;
    const int lane = tid & 63, wid = tid >> 6;
    const int base = blockIdx.x * 1024 + tid * 4;
    int4 c = {0, 0, 0, 0};
    if (base + 3 < N) c = *(const int4*)(counts + base);
    else {
        if (base + 0 < N) c.x = counts[base + 0];
        if (base + 1 < N) c.y = counts[base + 1];
        if (base + 2 < N) c.z = counts[base + 2];
        if (base + 3 < N) c.w = counts[base + 3];
    }
    int p1 = c.x, p2 = p1 + c.y, p3 = p2 + c.z, p4 = p3 + c.w;
    int s = p4;
#pragma unroll
    for (int off = 1; off < 64; off <<= 1) {
        int t = __shfl_up(s, off, 64);
        if (lane >= off) s += t;
    }
    __shared__ int ws[4];
    if (lane == 63) ws[wid] = s;
    __syncthreads();
    int wbase = 0;
#pragma unroll
    for (int w = 0; w < 4; ++w) wbase += (w < wid) ? ws[w] : 0;
    int excl = partials[blockIdx.x] + wbase + (s - p4);
    if (base + 0 < N) offsets[base + 1] = excl + p1;
    if (base + 1 < N) offsets[base + 2] = excl + p2;
    if (base + 2 < N) offsets[base + 3] = excl + p3;
    if (base + 3 < N) offsets[base + 4] = excl + p4;
    if (blockIdx.x == 0 && tid == 0) offsets[0] = 0;
}

// ---------------------------------------------------------------------------
// Phase C: bucket fill from compact slice lists; cursor + bucket region for a
// slice stay L2-local, reads are slice-local (no eviction pressure).
__global__ void fill2_kernel(const int* __restrict__ dstL, const int* __restrict__ payL,
                             const int* __restrict__ tail, const int* __restrict__ offsets,
                             int* __restrict__ cursor, int* __restrict__ bucket,
                             int cap, int stride) {
    const int slice = blockIdx.x & 7;
    const int group = blockIdx.x >> 3;
    const int len = tail[slice];
    const int* dl = dstL + (size_t)slice * cap;
    const int* pl = payL + (size_t)slice * cap;
    for (int i = group * 256 + threadIdx.x; i < len; i += stride) {
        int dst = dl[i];
        int pos = offsets[dst] + atomicAdd(&cursor[dst], 1);
        bucket[pos] = pl[i];
    }
}

// ---------------------------------------------------------------------------
// comb[layer][c][d] = bf16( b0[a0][d] + b1[a1][d] + b2[a2][d] )
__global__ void comb_kernel(const float* __restrict__ bond_emb, unsigned short* __restrict__ comb) {
    int idx = blockIdx.x * 256 + threadIdx.x;  // c*128 + d
    if (idx >= 216 * D) return;
    int c = idx >> 7, d = idx & 127;
    int a0 = c / 36, a1 = (c / 6) % 6, a2 = c % 6;
    const float* b = bond_emb + (size_t)blockIdx.y * 3 * 6 * D;
    float v = b[(0 * 6 + a0) * D + d] + b[(1 * 6 + a1) * D + d] + b[(2 * 6 + a2) * D + d];
    comb[(size_t)blockIdx.y * 216 * D + idx] = f2bf(v);
}

// ---------------------------------------------------------------------------
// Pack W [K][NCOLS] fp32 row-major -> Wp[k/32][n][k%32] bf16 (MFMA B-fragment order).
__global__ void pack_w_kernel(const float* __restrict__ W, unsigned short* __restrict__ Wp,
                              int total, int logN) {
    int idx = blockIdx.x * 256 + threadIdx.x;
    if (idx >= total) return;
    int NCOLS = 1 << logN;
    int k = idx >> logN, n = idx & (NCOLS - 1);
    const float* Wl = W + (size_t)blockIdx.y * total;
    unsigned short* Wpl = Wp + (size_t)blockIdx.y * total;
    Wpl[((size_t)(k >> 5) * NCOLS + n) * 32 + (k & 31)] = f2bf(Wl[idx]);
}

// ---------------------------------------------------------------------------
// pre[n] = bf16( (1+eps)*h[n] + sum_{e in in(n)} relu(h[src_e] + comb[c_e]) )
__global__ __launch_bounds__(256)
void gather_reduce_kernel(const int* __restrict__ offsets, const int* __restrict__ bucket,
                          const unsigned short* __restrict__ comb,
                          const unsigned short* __restrict__ hb,
                          const float* __restrict__ eps_l,
                          unsigned short* __restrict__ pre, int N) {
    int gid = blockIdx.x * blockDim.x + threadIdx.x;
    int node = gid >> 4;
    if (node >= N) return;
    int d0 = (gid & 15) * 8;

    union U8 { int4 i; unsigned short u[8]; };
    float s = 1.0f + eps_l[0];
    float a[8];
    {
        U8 hv; hv.i = *(const int4*)(hb + (size_t)node * D + d0);
#pragma unroll
        for (int j = 0; j < 8; ++j) a[j] = bf2f(hv.u[j]) * s;
    }
    const int beg = offsets[node], end = offsets[node + 1];
    for (int p = beg; p < end; p += 4) {
        int rem = end - p;
        int pk0 = bucket[p];
        int pk1 = bucket[rem > 1 ? p + 1 : p];
        int pk2 = bucket[rem > 2 ? p + 2 : p];
        int pk3 = bucket[rem > 3 ? p + 3 : p];
        U8 h0, h1, h2, h3, c0, c1, c2, c3;
        h0.i = *(const int4*)(hb + (size_t)(pk0 & 0x1FFFF) * D + d0);
        c0.i = *(const int4*)(comb + (size_t)((pk0 >> 17) & 0xFF) * D + d0);
        h1.i = *(const int4*)(hb + (size_t)(pk1 & 0x1FFFF) * D + d0);
        c1.i = *(const int4*)(comb + (size_t)((pk1 >> 17) & 0xFF) * D + d0);
        h2.i = *(const int4*)(hb + (size_t)(pk2 & 0x1FFFF) * D + d0);
        c2.i = *(const int4*)(comb + (size_t)((pk2 >> 17) & 0xFF) * D + d0);
        h3.i = *(const int4*)(hb + (size_t)(pk3 & 0x1FFFF) * D + d0);
        c3.i = *(const int4*)(comb + (size_t)((pk3 >> 17) & 0xFF) * D + d0);
#pragma unroll
        for (int j = 0; j < 8; ++j) a[j] += fmaxf(bf2f(h0.u[j]) + bf2f(c0.u[j]), 0.0f);
        if (rem > 1) {
#pragma unroll
            for (int j = 0; j < 8; ++j) a[j] += fmaxf(bf2f(h1.u[j]) + bf2f(c1.u[j]), 0.0f);
        }
        if (rem > 2) {
#pragma unroll
            for (int j = 0; j < 8; ++j) a[j] += fmaxf(bf2f(h2.u[j]) + bf2f(c2.u[j]), 0.0f);
        }
        if (rem > 3) {
#pragma unroll
            for (int j = 0; j < 8; ++j) a[j] += fmaxf(bf2f(h3.u[j]) + bf2f(c3.u[j]), 0.0f);
        }
    }
    U8 o;
#pragma unroll
    for (int j = 0; j < 8; ++j) o.u[j] = f2bf(a[j]);
    *(int4*)(pre + (size_t)node * D + d0) = o.i;
}

// ---------------------------------------------------------------------------
// MFMA GEMM with fused per-column sum/sum-sq -> NON-ATOMIC per-block partials.
template <int K, int NCOLS, int TRANSFORM, int OUTBF>
__global__ __launch_bounds__(256)
void mfma_gemm_kernel(const unsigned short* __restrict__ A,
                      const unsigned short* __restrict__ Wp,
                      const float* __restrict__ bias,
                      const float* __restrict__ tscale, const float* __restrict__ tshift,
                      unsigned short* __restrict__ Cbf, float* __restrict__ Cf,
                      float* __restrict__ partial, int M) {
    constexpr int NT = NCOLS / 16;
    __shared__ float red[NCOLS * 2];
    const int tid = threadIdx.x;
    for (int i = tid; i < NCOLS * 2; i += 256) red[i] = 0.f;

    const int wave = tid >> 6, lane = tid & 63;
    const int quad = lane >> 4, ln = lane & 15;
    const int m_base = blockIdx.x * 64 + wave * 16;
    int arow = m_base + ln;
    if (arow >= M) arow = M - 1;
    const int kq = quad * 8;

    floatx4 acc[NT];
#pragma unroll
    for (int t = 0; t < NT; ++t) acc[t] = (floatx4){0.f, 0.f, 0.f, 0.f};

#pragma unroll
    for (int k0 = 0; k0 < K; k0 += 32) {
        short8 afrag;
        if constexpr (TRANSFORM) {
            union { int4 i; unsigned short u[8]; } raw;
            raw.i = *(const int4*)(A + (size_t)arow * K + k0 + kq);
            float4 sc0 = *(const float4*)(tscale + k0 + kq);
            float4 sc1 = *(const float4*)(tscale + k0 + kq + 4);
            float4 sh0 = *(const float4*)(tshift + k0 + kq);
            float4 sh1 = *(const float4*)(tshift + k0 + kq + 4);
            union { short8 v; unsigned short u[8]; } au;
            au.u[0] = f2bf(fmaxf(bf2f(raw.u[0]) * sc0.x + sh0.x, 0.f));
            au.u[1] = f2bf(fmaxf(bf2f(raw.u[1]) * sc0.y + sh0.y, 0.f));
            au.u[2] = f2bf(fmaxf(bf2f(raw.u[2]) * sc0.z + sh0.z, 0.f));
            au.u[3] = f2bf(fmaxf(bf2f(raw.u[3]) * sc0.w + sh0.w, 0.f));
            au.u[4] = f2bf(fmaxf(bf2f(raw.u[4]) * sc1.x + sh1.x, 0.f));
            au.u[5] = f2bf(fmaxf(bf2f(raw.u[5]) * sc1.y + sh1.y, 0.f));
            au.u[6] = f2bf(fmaxf(bf2f(raw.u[6]) * sc1.z + sh1.z, 0.f));
            au.u[7] = f2bf(fmaxf(bf2f(raw.u[7]) * sc1.w + sh1.w, 0.f));
            afrag = au.v;
        } else {
            afrag = *(const short8*)(A + (size_t)arow * K + k0 + kq);
        }
#pragma unroll
        for (int t = 0; t < NT; ++t) {
            short8 bfrag = *(const short8*)(Wp + ((size_t)(k0 >> 5) * NCOLS + (t * 16 + ln)) * 32 + kq);
            acc[t] = __builtin_amdgcn_mfma_f32_16x16x32_bf16(afrag, bfrag, acc[t], 0, 0, 0);
        }
    }

    __syncthreads();  // red[] zero-init visible
#pragma unroll
    for (int t = 0; t < NT; ++t) {
        int col = t * 16 + ln;
        float bv = bias[col];
        float sv = 0.f, qv = 0.f;
#pragma unroll
        for (int r = 0; r < 4; ++r) {
            int row = m_base + quad * 4 + r;
            if (row < M) {
                float v = acc[t][r] + bv;
                sv += v; qv += v * v;
                if constexpr (OUTBF) Cbf[(size_t)row * NCOLS + col] = f2bf(v);
                else                 Cf[(size_t)row * NCOLS + col] = v;
            }
        }
        sv += __shfl_xor(sv, 16, 64); sv += __shfl_xor(sv, 32, 64);
        qv += __shfl_xor(qv, 16, 64); qv += __shfl_xor(qv, 32, 64);
        if (quad == 0) {
            atomicAdd(&red[col], sv);          // LDS atomics: 4 waves only, cheap
            atomicAdd(&red[NCOLS + col], qv);
        }
    }
    __syncthreads();
    float* pout = partial + (size_t)blockIdx.x * (NCOLS * 2);
    for (int i = tid; i < NCOLS * 2; i += 256) pout[i] = red[i];  // non-atomic, coalesced
}

// ---------------------------------------------------------------------------
// One block per column: tree-reduce per-block partials, emit scale/shift.
template <int NCOLS>
__global__ __launch_bounds__(256)
void reduce_stats_kernel(const float* __restrict__ partial, int nb,
                         const float* __restrict__ g, const float* __restrict__ b,
                         float* __restrict__ scale, float* __restrict__ shift, float invN) {
    const int col = blockIdx.x;
    const int tid = threadIdx.x;
    float s = 0.f, q = 0.f;
    for (int bb = tid; bb < nb; bb += 256) {
        const float* p = partial + (size_t)bb * (NCOLS * 2);
        s += p[col];
        q += p[NCOLS + col];
    }
#pragma unroll
    for (int off = 32; off > 0; off >>= 1) {
        s += __shfl_xor(s, off, 64);
        q += __shfl_xor(q, off, 64);
    }
    __shared__ float ws[4], wq[4];
    if ((tid & 63) == 0) { ws[tid >> 6] = s; wq[tid >> 6] = q; }
    __syncthreads();
    if (tid == 0) {
        s = ws[0] + ws[1] + ws[2] + ws[3];
        q = wq[0] + wq[1] + wq[2] + wq[3];
        float mean = s * invN;
        float var = q * invN - mean * mean;
        float inv = 1.0f / sqrtf(var + BN_EPS);
        float sc = g[col] * inv;
        scale[col] = sc;
        shift[col] = b[col] - mean * sc;
    }
}

// ---------------------------------------------------------------------------
// mode 0: hb = bf16(relu(bn(out2)))   mode 1: h = bn(out2) fp32 (final)
__global__ void bn_apply_kernel(const float* __restrict__ X, float* __restrict__ Yf,
                                unsigned short* __restrict__ Yb,
                                const float* __restrict__ scale, const float* __restrict__ shift,
                                int N, int mode) {
    int gid = blockIdx.x * blockDim.x + threadIdx.x;
    int node = gid >> 5;
    if (node >= N) return;
    int d0 = (gid & 31) * 4;
    float4 v = *(const float4*)(X + (size_t)node * D + d0);
    float4 sc = *(const float4*)(scale + d0);
    float4 sh = *(const float4*)(shift + d0);
    float4 o;
    o.x = v.x * sc.x + sh.x;
    o.y = v.y * sc.y + sh.y;
    o.z = v.z * sc.z + sh.z;
    o.w = v.w * sc.w + sh.w;
    if (mode == 0) {
        ushort4 ob;
        ob.x = f2bf(fmaxf(o.x, 0.f));
        ob.y = f2bf(fmaxf(o.y, 0.f));
        ob.z = f2bf(fmaxf(o.z, 0.f));
        ob.w = f2bf(fmaxf(o.w, 0.f));
        *(ushort4*)(Yb + (size_t)node * D + d0) = ob;
    } else {
        *(float4*)(Yf + (size_t)node * D + d0) = o;
    }
}

// ---------------------------------------------------------------------------
extern "C" void kernel_launch(void* const* d_in, const int* in_sizes, int n_in,
                              void* d_out, int out_size, void* d_ws, size_t ws_size,
                              hipStream_t stream) {
    const int*   x        = (const int*)d_in[0];
    const int*   z        = (const int*)d_in[1];
    const int*   ei       = (const int*)d_in[2];
    const int*   ea       = (const int*)d_in[3];
    const float* atom_emb = (const float*)d_in[4];
    const float* z_emb    = (const float*)d_in[5];
    const float* bond_emb = (const float*)d_in[6];
    const float* eps      = (const float*)d_in[7];
    const float* W1       = (const float*)d_in[8];
    const float* b1       = (const float*)d_in[9];
    const float* g1       = (const float*)d_in[10];
    const float* be1      = (const float*)d_in[11];
    const float* W2       = (const float*)d_in[12];
    const float* b2       = (const float*)d_in[13];
    const float* bng      = (const float*)d_in[14];
    const float* bnb      = (const float*)d_in[15];

    const int N = in_sizes[1];
    const int E = in_sizes[3] / 3;

    float* h = (float*)d_out;  // final [N,128] fp32

    const int ngb = (N + 63) / 64;  // GEMM grid
    const int cap = E / 8 + E / 32; // per-slice list capacity (~120 sigma margin)

    char* ws = (char*)d_ws;
    size_t off = 0;
    auto alloc = [&](size_t bytes) { void* p = ws + off; off += (bytes + 255) & ~(size_t)255; return p; };
    unsigned short* pre_bf = (unsigned short*)alloc((size_t)N * D * 2);      // 25.6 MB
    unsigned short* extra  = (unsigned short*)alloc((size_t)N * D * 2);      // 25.6 MB (out2 tail)
    (void)extra;
    float* out2 = (float*)pre_bf;                                            // spans pre_bf+extra
    unsigned short* out1_bf = (unsigned short*)alloc((size_t)N * 2 * D * 2); // 51.2 MB
    unsigned short* hb      = (unsigned short*)alloc((size_t)N * D * 2);     // 25.6 MB
    int* offsets = (int*)alloc((size_t)(N + 1) * 4);
    int* bucket  = (int*)alloc((size_t)E * 4);
    int* dstL    = (int*)alloc((size_t)8 * cap * 4);   // 8 MB
    int* payL    = (int*)alloc((size_t)8 * cap * 4);   // 8 MB
    float* stats = (float*)alloc(1024 * 4);
    int* spart   = (int*)alloc(128 * 4);
    float* partial1 = (float*)alloc((size_t)ngb * 512 * 4);  // 3.2 MB
    float* partial2 = (float*)alloc((size_t)ngb * 256 * 4);  // 1.6 MB
    unsigned short* w1p  = (unsigned short*)alloc((size_t)2 * D * 2 * D * 2);
    unsigned short* w2p  = (unsigned short*)alloc((size_t)2 * 2 * D * D * 2);
    unsigned short* comb = (unsigned short*)alloc((size_t)2 * 216 * D * 2);
    // transient: counts/cursor/tail alias out1_bf (dead until first GEMM1 write)
    int* counts = (int*)out1_bf;
    int* cursor = counts + N;
    int* tail   = cursor + N;   // 8 ints

    float* scale1 = stats;          // 256
    float* shift1 = stats + 256;    // 256
    float* scale2 = stats + 512;    // 128
    float* shift2 = stats + 640;    // 128

    const float invN = 1.0f / (float)N;
    const int nb = (N + 1023) / 1024;
    const int ntiles = (E + 4095) / 4096;
    const int SLICED_BLOCKS = 512;            // 64 groups x 8 slices
    const int SLICED_STRIDE = 64 * 256;

    // --- CSR build: partition -> hist -> scan -> fill ---
    hipMemsetAsync(counts, 0, ((size_t)N * 2 + 8) * sizeof(int), stream);
    partition_kernel<<<256, 256, 0, stream>>>(ei, ea, dstL, payL, tail, E, N, cap, ntiles, 256);
    hist2_kernel<<<SLICED_BLOCKS, 256, 0, stream>>>(dstL, tail, counts, cap, SLICED_STRIDE);
    scan_p1_kernel<<<nb, 256, 0, stream>>>(counts, spart, N);
    scan_p2_kernel<<<1, 128, 0, stream>>>(spart, nb);
    scan_p3_kernel<<<nb, 256, 0, stream>>>(counts, spart, offsets, N);
    fill2_kernel<<<SLICED_BLOCKS, 256, 0, stream>>>(dstL, payL, tail, offsets, cursor, bucket,
                                                    cap, SLICED_STRIDE);

    node_init_kernel<<<(N * 32 + 255) / 256, 256, 0, stream>>>(x, z, atom_emb, z_emb, hb, N);
    comb_kernel<<<dim3((216 * D + 255) / 256, 2), 256, 0, stream>>>(bond_emb, comb);
    pack_w_kernel<<<dim3((D * 2 * D + 255) / 256, 2), 256, 0, stream>>>(W1, w1p, D * 2 * D, 8);
    pack_w_kernel<<<dim3((2 * D * D + 255) / 256, 2), 256, 0, stream>>>(W2, w2p, 2 * D * D, 7);

    for (int l = 0; l < 2; ++l) {
        gather_reduce_kernel<<<(N * 16 + 255) / 256, 256, 0, stream>>>(
            offsets, bucket, comb + (size_t)l * 216 * D, hb, eps + l, pre_bf, N);

        mfma_gemm_kernel<128, 256, 0, 1><<<ngb, 256, 0, stream>>>(
            pre_bf, w1p + (size_t)l * D * 2 * D, b1 + (size_t)l * 2 * D,
            nullptr, nullptr, out1_bf, nullptr, partial1, N);
        reduce_stats_kernel<256><<<256, 256, 0, stream>>>(
            partial1, ngb, g1 + (size_t)l * 2 * D, be1 + (size_t)l * 2 * D,
            scale1, shift1, invN);

        mfma_gemm_kernel<256, 128, 1, 0><<<ngb, 256, 0, stream>>>(
            out1_bf, w2p + (size_t)l * 2 * D * D, b2 + (size_t)l * D,
            scale1, shift1, nullptr, out2, partial2, N);
        reduce_stats_kernel<128><<<128, 256, 0, stream>>>(
            partial2, ngb, bng + (size_t)l * D, bnb + (size_t)l * D,
            scale2, shift2, invN);

        bn_apply_kernel<<<(N * 32 + 255) / 256, 256, 0, stream>>>(out2, h, hb, scale2, shift2,
                                                                  N, l == 0 ? 0 : 1);
    }
}

// Round 7
// 679.957 us; speedup vs baseline: 1.0927x; 1.0927x over previous
//
#include <hip/hip_runtime.h>

#define D 128
#define BN_EPS 1e-5f

typedef __attribute__((ext_vector_type(8))) short short8;   // 8 x bf16 (4 VGPRs)
typedef __attribute__((ext_vector_type(4))) float floatx4;  // MFMA accumulator

__device__ __forceinline__ float bf2f(unsigned short u) {
    unsigned int x = ((unsigned int)u) << 16;
    return __builtin_bit_cast(float, x);
}
__device__ __forceinline__ unsigned short f2bf(float f) {
    unsigned int x = __builtin_bit_cast(unsigned int, f);
    x = x + 0x7FFFu + ((x >> 16) & 1u);  // round-to-nearest-even
    return (unsigned short)(x >> 16);
}

// ---------------------------------------------------------------------------
// hb0 = bf16( sum_f atom_emb[f, x[n,f], :] + z_emb[z[n], :] )
__global__ void node_init_kernel(const int* __restrict__ x, const int* __restrict__ z,
                                 const float* __restrict__ atom_emb,
                                 const float* __restrict__ z_emb,
                                 unsigned short* __restrict__ hb, int N) {
    int gid = blockIdx.x * blockDim.x + threadIdx.x;
    int node = gid >> 5;
    if (node >= N) return;
    int d0 = (gid & 31) * 4;
    float4 acc = *(const float4*)(z_emb + (size_t)z[node] * D + d0);
#pragma unroll
    for (int f = 0; f < 9; ++f) {
        int v = x[node * 9 + f];
        const float4 t = *(const float4*)(atom_emb + (size_t)(f * 119 + v) * D + d0);
        acc.x += t.x; acc.y += t.y; acc.z += t.z; acc.w += t.w;
    }
    ushort4 o;
    o.x = f2bf(acc.x); o.y = f2bf(acc.y); o.z = f2bf(acc.z); o.w = f2bf(acc.w);
    *(ushort4*)(hb + (size_t)node * D + d0) = o;
}

// ---------------------------------------------------------------------------
// Phase A: single pass over edges -> 8 compact per-dst-slice lists.
__global__ __launch_bounds__(256)
void partition_kernel(const int* __restrict__ ei, const int* __restrict__ ea,
                      int* __restrict__ dstL, int* __restrict__ payL,
                      int* __restrict__ tail, int E, int N, int cap,
                      int ntiles, int nblocks) {
    __shared__ int lcnt[8], lbase[8];
    const int tid = threadIdx.x;
    for (int tile = blockIdx.x; tile < ntiles; tile += nblocks) {
        const int tb = tile * 4096;
        if (tid < 8) lcnt[tid] = 0;
        __syncthreads();
        int mydst[16], mypay[16];
#pragma unroll
        for (int j = 0; j < 16; ++j) {
            int e = tb + j * 256 + tid;
            if (e < E) {
                int dst = ei[E + e];
                int src = ei[e];
                int c = (ea[3 * e] * 6 + ea[3 * e + 1]) * 6 + ea[3 * e + 2];
                mydst[j] = dst;
                mypay[j] = src | (c << 17);
                int s = (int)((8LL * dst) / N);
                atomicAdd(&lcnt[s], 1);
            } else {
                mydst[j] = -1;
            }
        }
        __syncthreads();
        if (tid < 8) {
            lbase[tid] = atomicAdd(&tail[tid], lcnt[tid]);
            lcnt[tid] = 0;
        }
        __syncthreads();
#pragma unroll
        for (int j = 0; j < 16; ++j) {
            if (mydst[j] >= 0) {
                int s = (int)((8LL * mydst[j]) / N);
                int pos = lbase[s] + atomicAdd(&lcnt[s], 1);
                dstL[(size_t)s * cap + pos] = mydst[j];
                payL[(size_t)s * cap + pos] = mypay[j];
            }
        }
        __syncthreads();
    }
}

// ---------------------------------------------------------------------------
// Phase B: in-degree histogram from compact slice lists.
__global__ void hist2_kernel(const int* __restrict__ dstL, const int* __restrict__ tail,
                             int* __restrict__ counts, int cap, int stride) {
    const int slice = blockIdx.x & 7;
    const int group = blockIdx.x >> 3;
    const int len = tail[slice];
    const int* dl = dstL + (size_t)slice * cap;
    for (int i = group * 256 + threadIdx.x; i < len; i += stride)
        atomicAdd(&counts[dl[i]], 1);
}

// ---------------------------------------------------------------------------
// Parallel exclusive scan of counts[N] -> offsets[N+1], 3 phases.
__global__ void scan_p1_kernel(const int* __restrict__ counts, int* __restrict__ partials, int N) {
    const int tid = threadIdx.x;
    const int base = blockIdx.x * 1024 + tid * 4;
    int4 c = {0, 0, 0, 0};
    if (base + 3 < N) c = *(const int4*)(counts + base);
    else {
        if (base + 0 < N) c.x = counts[base + 0];
        if (base + 1 < N) c.y = counts[base + 1];
        if (base + 2 < N) c.z = counts[base + 2];
        if (base + 3 < N) c.w = counts[base + 3];
    }
    int s = c.x + c.y + c.z + c.w;
#pragma unroll
    for (int off = 32; off > 0; off >>= 1) s += __shfl_xor(s, off, 64);
    __shared__ int ws[4];
    if ((tid & 63) == 0) ws[tid >> 6] = s;
    __syncthreads();
    if (tid == 0) partials[blockIdx.x] = ws[0] + ws[1] + ws[2] + ws[3];
}

__global__ void scan_p2_kernel(int* __restrict__ partials, int nb) {
    const int tid = threadIdx.x;  // 128 threads, nb <= 128
    const int lane = tid & 63, wid = tid >> 6;
    int v = (tid < nb) ? partials[tid] : 0;
    int s = v;
#pragma unroll
    for (int off = 1; off < 64; off <<= 1) {
        int t = __shfl_up(s, off, 64);
        if (lane >= off) s += t;
    }
    __shared__ int ws2[2];
    if (lane == 63) ws2[wid] = s;
    __syncthreads();
    if (wid == 1) s += ws2[0];
    if (tid < nb) partials[tid] = s - v;  // exclusive
}

__global__ void scan_p3_kernel(const int* __restrict__ counts, const int* __restrict__ partials,
                               int* __restrict__ offsets, int N) {
    const int tid = threadIdx.x;
    const int lane = tid & 63, wid = tid >> 6;
    const int base = blockIdx.x * 1024 + tid * 4;
    int4 c = {0, 0, 0, 0};
    if (base + 3 < N) c = *(const int4*)(counts + base);
    else {
        if (base + 0 < N) c.x = counts[base + 0];
        if (base + 1 < N) c.y = counts[base + 1];
        if (base + 2 < N) c.z = counts[base + 2];
        if (base + 3 < N) c.w = counts[base + 3];
    }
    int p1 = c.x, p2 = p1 + c.y, p3 = p2 + c.z, p4 = p3 + c.w;
    int s = p4;
#pragma unroll
    for (int off = 1; off < 64; off <<= 1) {
        int t = __shfl_up(s, off, 64);
        if (lane >= off) s += t;
    }
    __shared__ int ws[4];
    if (lane == 63) ws[wid] = s;
    __syncthreads();
    int wbase = 0;
#pragma unroll
    for (int w = 0; w < 4; ++w) wbase += (w < wid) ? ws[w] : 0;
    int excl = partials[blockIdx.x] + wbase + (s - p4);
    if (base + 0 < N) offsets[base + 1] = excl + p1;
    if (base + 1 < N) offsets[base + 2] = excl + p2;
    if (base + 2 < N) offsets[base + 3] = excl + p3;
    if (base + 3 < N) offsets[base + 4] = excl + p4;
    if (blockIdx.x == 0 && tid == 0) offsets[0] = 0;
}

// ---------------------------------------------------------------------------
// Phase C: bucket fill from compact slice lists.
__global__ void fill2_kernel(const int* __restrict__ dstL, const int* __restrict__ payL,
                             const int* __restrict__ tail, const int* __restrict__ offsets,
                             int* __restrict__ cursor, int* __restrict__ bucket,
                             int cap, int stride) {
    const int slice = blockIdx.x & 7;
    const int group = blockIdx.x >> 3;
    const int len = tail[slice];
    const int* dl = dstL + (size_t)slice * cap;
    const int* pl = payL + (size_t)slice * cap;
    for (int i = group * 256 + threadIdx.x; i < len; i += stride) {
        int dst = dl[i];
        int pos = offsets[dst] + atomicAdd(&cursor[dst], 1);
        bucket[pos] = pl[i];
    }
}

// ---------------------------------------------------------------------------
// comb[layer][c][d] = bf16( b0[a0][d] + b1[a1][d] + b2[a2][d] )
__global__ void comb_kernel(const float* __restrict__ bond_emb, unsigned short* __restrict__ comb) {
    int idx = blockIdx.x * 256 + threadIdx.x;  // c*128 + d
    if (idx >= 216 * D) return;
    int c = idx >> 7, d = idx & 127;
    int a0 = c / 36, a1 = (c / 6) % 6, a2 = c % 6;
    const float* b = bond_emb + (size_t)blockIdx.y * 3 * 6 * D;
    float v = b[(0 * 6 + a0) * D + d] + b[(1 * 6 + a1) * D + d] + b[(2 * 6 + a2) * D + d];
    comb[(size_t)blockIdx.y * 216 * D + idx] = f2bf(v);
}

// ---------------------------------------------------------------------------
// Pack W [K][NCOLS] fp32 row-major -> FRAGMENT-LINEAR order:
//   dest = ((k/32)*NT + n/16)*512 + ((kq/8)*16 + n%16)*8 + kq%8,  kq=k%32, NT=NCOLS/16
// so a wave's 64 lanes read consecutive 16B chunks (conflict-free LDS, linear staging).
__global__ void pack_w_kernel(const float* __restrict__ W, unsigned short* __restrict__ Wp,
                              int total, int logN) {
    int idx = blockIdx.x * 256 + threadIdx.x;
    if (idx >= total) return;
    int NCOLS = 1 << logN;
    int k = idx >> logN, n = idx & (NCOLS - 1);
    int k0 = k >> 5, kq = k & 31, q = kq >> 3, j = kq & 7;
    int t = n >> 4, ln = n & 15;
    size_t dest = (((size_t)k0 * (NCOLS >> 4) + t) << 9) + ((q << 4) + ln) * 8 + j;
    const float* Wl = W + (size_t)blockIdx.y * total;
    unsigned short* Wpl = Wp + (size_t)blockIdx.y * total;
    Wpl[dest] = f2bf(Wl[idx]);
}

// ---------------------------------------------------------------------------
// pre[n] = bf16( (1+eps)*h[n] + sum_{e in in(n)} relu(h[src_e] + comb[c_e]) )
__global__ __launch_bounds__(256)
void gather_reduce_kernel(const int* __restrict__ offsets, const int* __restrict__ bucket,
                          const unsigned short* __restrict__ comb,
                          const unsigned short* __restrict__ hb,
                          const float* __restrict__ eps_l,
                          unsigned short* __restrict__ pre, int N) {
    int gid = blockIdx.x * blockDim.x + threadIdx.x;
    int node = gid >> 4;
    if (node >= N) return;
    int d0 = (gid & 15) * 8;

    union U8 { int4 i; unsigned short u[8]; };
    float s = 1.0f + eps_l[0];
    float a[8];
    {
        U8 hv; hv.i = *(const int4*)(hb + (size_t)node * D + d0);
#pragma unroll
        for (int j = 0; j < 8; ++j) a[j] = bf2f(hv.u[j]) * s;
    }
    const int beg = offsets[node], end = offsets[node + 1];
    for (int p = beg; p < end; p += 4) {
        int rem = end - p;
        int pk0 = bucket[p];
        int pk1 = bucket[rem > 1 ? p + 1 : p];
        int pk2 = bucket[rem > 2 ? p + 2 : p];
        int pk3 = bucket[rem > 3 ? p + 3 : p];
        U8 h0, h1, h2, h3, c0, c1, c2, c3;
        h0.i = *(const int4*)(hb + (size_t)(pk0 & 0x1FFFF) * D + d0);
        c0.i = *(const int4*)(comb + (size_t)((pk0 >> 17) & 0xFF) * D + d0);
        h1.i = *(const int4*)(hb + (size_t)(pk1 & 0x1FFFF) * D + d0);
        c1.i = *(const int4*)(comb + (size_t)((pk1 >> 17) & 0xFF) * D + d0);
        h2.i = *(const int4*)(hb + (size_t)(pk2 & 0x1FFFF) * D + d0);
        c2.i = *(const int4*)(comb + (size_t)((pk2 >> 17) & 0xFF) * D + d0);
        h3.i = *(const int4*)(hb + (size_t)(pk3 & 0x1FFFF) * D + d0);
        c3.i = *(const int4*)(comb + (size_t)((pk3 >> 17) & 0xFF) * D + d0);
#pragma unroll
        for (int j = 0; j < 8; ++j) a[j] += fmaxf(bf2f(h0.u[j]) + bf2f(c0.u[j]), 0.0f);
        if (rem > 1) {
#pragma unroll
            for (int j = 0; j < 8; ++j) a[j] += fmaxf(bf2f(h1.u[j]) + bf2f(c1.u[j]), 0.0f);
        }
        if (rem > 2) {
#pragma unroll
            for (int j = 0; j < 8; ++j) a[j] += fmaxf(bf2f(h2.u[j]) + bf2f(c2.u[j]), 0.0f);
        }
        if (rem > 3) {
#pragma unroll
            for (int j = 0; j < 8; ++j) a[j] += fmaxf(bf2f(h3.u[j]) + bf2f(c3.u[j]), 0.0f);
        }
    }
    U8 o;
#pragma unroll
    for (int j = 0; j < 8; ++j) o.u[j] = f2bf(a[j]);
    *(int4*)(pre + (size_t)node * D + d0) = o.i;
}

// ---------------------------------------------------------------------------
// MFMA GEMM, B staged in LDS (2 x 32KB phases, fragment-linear = conflict-free
// ds_read_b128), all A-chunks prefetched upfront; fused per-column stats ->
// non-atomic per-block partials.
template <int K, int NCOLS, int TRANSFORM, int OUTBF>
__global__ __launch_bounds__(256)
void mfma_gemm_kernel(const unsigned short* __restrict__ A,
                      const unsigned short* __restrict__ Wp,
                      const float* __restrict__ bias,
                      const float* __restrict__ tscale, const float* __restrict__ tshift,
                      unsigned short* __restrict__ Cbf, float* __restrict__ Cf,
                      float* __restrict__ partial, int M) {
    constexpr int NT = NCOLS / 16;       // n-tiles
    constexpr int NCHUNK = K / 32;       // k-chunks
    constexpr int CPP = NCHUNK / 2;      // chunks per phase (K*NCOLS/2 = 16384 elems)
    __shared__ unsigned short Ws[16384]; // 32 KB
    __shared__ float red[NCOLS * 2];

    const int tid = threadIdx.x;
    const int wave = tid >> 6, lane = tid & 63;
    const int quad = lane >> 4, ln = lane & 15;
    const int m_base = blockIdx.x * 64 + wave * 16;
    int arow = m_base + ln;
    if (arow >= M) arow = M - 1;
    const int kq = quad * 8;

    // Prefetch ALL A chunks (independent loads, in flight during LDS staging).
    int4 araw[NCHUNK];
#pragma unroll
    for (int c = 0; c < NCHUNK; ++c)
        araw[c] = *(const int4*)(A + (size_t)arow * K + c * 32 + kq);

    for (int i = tid; i < NCOLS * 2; i += 256) red[i] = 0.f;

    floatx4 acc[NT];
#pragma unroll
    for (int t = 0; t < NT; ++t) acc[t] = (floatx4){0.f, 0.f, 0.f, 0.f};

#pragma unroll
    for (int ph = 0; ph < 2; ++ph) {
        if (ph) __syncthreads();  // drain phase-0 readers before overwrite
        // Linear coalesced staging of this phase's fragments.
#pragma unroll
        for (int i = 0; i < 16384; i += 2048)
            *(int4*)&Ws[i + tid * 8] = *(const int4*)&Wp[ph * 16384 + i + tid * 8];
        __syncthreads();
#pragma unroll
        for (int cc = 0; cc < CPP; ++cc) {
            const int c = ph * CPP + cc;
            short8 afrag;
            if constexpr (TRANSFORM) {
                union { int4 i; unsigned short u[8]; } raw;
                raw.i = araw[c];
                const int kb = c * 32 + kq;
                float4 sc0 = *(const float4*)(tscale + kb);
                float4 sc1 = *(const float4*)(tscale + kb + 4);
                float4 sh0 = *(const float4*)(tshift + kb);
                float4 sh1 = *(const float4*)(tshift + kb + 4);
                union { short8 v; unsigned short u[8]; } au;
                au.u[0] = f2bf(fmaxf(bf2f(raw.u[0]) * sc0.x + sh0.x, 0.f));
                au.u[1] = f2bf(fmaxf(bf2f(raw.u[1]) * sc0.y + sh0.y, 0.f));
                au.u[2] = f2bf(fmaxf(bf2f(raw.u[2]) * sc0.z + sh0.z, 0.f));
                au.u[3] = f2bf(fmaxf(bf2f(raw.u[3]) * sc0.w + sh0.w, 0.f));
                au.u[4] = f2bf(fmaxf(bf2f(raw.u[4]) * sc1.x + sh1.x, 0.f));
                au.u[5] = f2bf(fmaxf(bf2f(raw.u[5]) * sc1.y + sh1.y, 0.f));
                au.u[6] = f2bf(fmaxf(bf2f(raw.u[6]) * sc1.z + sh1.z, 0.f));
                au.u[7] = f2bf(fmaxf(bf2f(raw.u[7]) * sc1.w + sh1.w, 0.f));
                afrag = au.v;
            } else {
                afrag = __builtin_bit_cast(short8, araw[c]);
            }
#pragma unroll
            for (int t = 0; t < NT; ++t) {
                short8 bfrag = *(const short8*)&Ws[(((cc * NT) + t) << 9) + lane * 8];
                acc[t] = __builtin_amdgcn_mfma_f32_16x16x32_bf16(afrag, bfrag, acc[t], 0, 0, 0);
            }
        }
    }

#pragma unroll
    for (int t = 0; t < NT; ++t) {
        int col = t * 16 + ln;
        float bv = bias[col];
        float sv = 0.f, qv = 0.f;
#pragma unroll
        for (int r = 0; r < 4; ++r) {
            int row = m_base + quad * 4 + r;
            if (row < M) {
                float v = acc[t][r] + bv;
                sv += v; qv += v * v;
                if constexpr (OUTBF) Cbf[(size_t)row * NCOLS + col] = f2bf(v);
                else                 Cf[(size_t)row * NCOLS + col] = v;
            }
        }
        sv += __shfl_xor(sv, 16, 64); sv += __shfl_xor(sv, 32, 64);
        qv += __shfl_xor(qv, 16, 64); qv += __shfl_xor(qv, 32, 64);
        if (quad == 0) {
            atomicAdd(&red[col], sv);          // LDS atomics: 4 waves only, cheap
            atomicAdd(&red[NCOLS + col], qv);
        }
    }
    __syncthreads();
    float* pout = partial + (size_t)blockIdx.x * (NCOLS * 2);
    for (int i = tid; i < NCOLS * 2; i += 256) pout[i] = red[i];  // non-atomic, coalesced
}

// ---------------------------------------------------------------------------
// One block per column: tree-reduce per-block partials, emit scale/shift.
template <int NCOLS>
__global__ __launch_bounds__(256)
void reduce_stats_kernel(const float* __restrict__ partial, int nb,
                         const float* __restrict__ g, const float* __restrict__ b,
                         float* __restrict__ scale, float* __restrict__ shift, float invN) {
    const int col = blockIdx.x;
    const int tid = threadIdx.x;
    float s = 0.f, q = 0.f;
    for (int bb = tid; bb < nb; bb += 256) {
        const float* p = partial + (size_t)bb * (NCOLS * 2);
        s += p[col];
        q += p[NCOLS + col];
    }
#pragma unroll
    for (int off = 32; off > 0; off >>= 1) {
        s += __shfl_xor(s, off, 64);
        q += __shfl_xor(q, off, 64);
    }
    __shared__ float ws[4], wq[4];
    if ((tid & 63) == 0) { ws[tid >> 6] = s; wq[tid >> 6] = q; }
    __syncthreads();
    if (tid == 0) {
        s = ws[0] + ws[1] + ws[2] + ws[3];
        q = wq[0] + wq[1] + wq[2] + wq[3];
        float mean = s * invN;
        float var = q * invN - mean * mean;
        float inv = 1.0f / sqrtf(var + BN_EPS);
        float sc = g[col] * inv;
        scale[col] = sc;
        shift[col] = b[col] - mean * sc;
    }
}

// ---------------------------------------------------------------------------
// mode 0: hb = bf16(relu(bn(out2)))   mode 1: h = bn(out2) fp32 (final)
__global__ void bn_apply_kernel(const float* __restrict__ X, float* __restrict__ Yf,
                                unsigned short* __restrict__ Yb,
                                const float* __restrict__ scale, const float* __restrict__ shift,
                                int N, int mode) {
    int gid = blockIdx.x * blockDim.x + threadIdx.x;
    int node = gid >> 5;
    if (node >= N) return;
    int d0 = (gid & 31) * 4;
    float4 v = *(const float4*)(X + (size_t)node * D + d0);
    float4 sc = *(const float4*)(scale + d0);
    float4 sh = *(const float4*)(shift + d0);
    float4 o;
    o.x = v.x * sc.x + sh.x;
    o.y = v.y * sc.y + sh.y;
    o.z = v.z * sc.z + sh.z;
    o.w = v.w * sc.w + sh.w;
    if (mode == 0) {
        ushort4 ob;
        ob.x = f2bf(fmaxf(o.x, 0.f));
        ob.y = f2bf(fmaxf(o.y, 0.f));
        ob.z = f2bf(fmaxf(o.z, 0.f));
        ob.w = f2bf(fmaxf(o.w, 0.f));
        *(ushort4*)(Yb + (size_t)node * D + d0) = ob;
    } else {
        *(float4*)(Yf + (size_t)node * D + d0) = o;
    }
}

// ---------------------------------------------------------------------------
extern "C" void kernel_launch(void* const* d_in, const int* in_sizes, int n_in,
                              void* d_out, int out_size, void* d_ws, size_t ws_size,
                              hipStream_t stream) {
    const int*   x        = (const int*)d_in[0];
    const int*   z        = (const int*)d_in[1];
    const int*   ei       = (const int*)d_in[2];
    const int*   ea       = (const int*)d_in[3];
    const float* atom_emb = (const float*)d_in[4];
    const float* z_emb    = (const float*)d_in[5];
    const float* bond_emb = (const float*)d_in[6];
    const float* eps      = (const float*)d_in[7];
    const float* W1       = (const float*)d_in[8];
    const float* b1       = (const float*)d_in[9];
    const float* g1       = (const float*)d_in[10];
    const float* be1      = (const float*)d_in[11];
    const float* W2       = (const float*)d_in[12];
    const float* b2       = (const float*)d_in[13];
    const float* bng      = (const float*)d_in[14];
    const float* bnb      = (const float*)d_in[15];

    const int N = in_sizes[1];
    const int E = in_sizes[3] / 3;

    float* h = (float*)d_out;  // final [N,128] fp32

    const int ngb = (N + 63) / 64;  // GEMM grid
    const int cap = E / 8 + E / 32; // per-slice list capacity

    char* ws = (char*)d_ws;
    size_t off = 0;
    auto alloc = [&](size_t bytes) { void* p = ws + off; off += (bytes + 255) & ~(size_t)255; return p; };
    unsigned short* pre_bf = (unsigned short*)alloc((size_t)N * D * 2);      // 25.6 MB
    unsigned short* extra  = (unsigned short*)alloc((size_t)N * D * 2);      // 25.6 MB (out2 tail)
    (void)extra;
    float* out2 = (float*)pre_bf;                                            // spans pre_bf+extra
    unsigned short* out1_bf = (unsigned short*)alloc((size_t)N * 2 * D * 2); // 51.2 MB
    unsigned short* hb      = (unsigned short*)alloc((size_t)N * D * 2);     // 25.6 MB
    int* offsets = (int*)alloc((size_t)(N + 1) * 4);
    int* bucket  = (int*)alloc((size_t)E * 4);
    int* dstL    = (int*)alloc((size_t)8 * cap * 4);   // 8 MB
    int* payL    = (int*)alloc((size_t)8 * cap * 4);   // 8 MB
    float* stats = (float*)alloc(1024 * 4);
    int* spart   = (int*)alloc(128 * 4);
    float* partial1 = (float*)alloc((size_t)ngb * 512 * 4);  // 3.2 MB
    float* partial2 = (float*)alloc((size_t)ngb * 256 * 4);  // 1.6 MB
    unsigned short* w1p  = (unsigned short*)alloc((size_t)2 * D * 2 * D * 2);
    unsigned short* w2p  = (unsigned short*)alloc((size_t)2 * 2 * D * D * 2);
    unsigned short* comb = (unsigned short*)alloc((size_t)2 * 216 * D * 2);
    // transient: counts/cursor/tail alias out1_bf (dead until first GEMM1 write)
    int* counts = (int*)out1_bf;
    int* cursor = counts + N;
    int* tail   = cursor + N;   // 8 ints

    float* scale1 = stats;          // 256
    float* shift1 = stats + 256;    // 256
    float* scale2 = stats + 512;    // 128
    float* shift2 = stats + 640;    // 128

    const float invN = 1.0f / (float)N;
    const int nb = (N + 1023) / 1024;
    const int ntiles = (E + 4095) / 4096;
    const int SLICED_BLOCKS = 512;            // 64 groups x 8 slices
    const int SLICED_STRIDE = 64 * 256;

    // --- CSR build: partition -> hist -> scan -> fill ---
    hipMemsetAsync(counts, 0, ((size_t)N * 2 + 8) * sizeof(int), stream);
    partition_kernel<<<256, 256, 0, stream>>>(ei, ea, dstL, payL, tail, E, N, cap, ntiles, 256);
    hist2_kernel<<<SLICED_BLOCKS, 256, 0, stream>>>(dstL, tail, counts, cap, SLICED_STRIDE);
    scan_p1_kernel<<<nb, 256, 0, stream>>>(counts, spart, N);
    scan_p2_kernel<<<1, 128, 0, stream>>>(spart, nb);
    scan_p3_kernel<<<nb, 256, 0, stream>>>(counts, spart, offsets, N);
    fill2_kernel<<<SLICED_BLOCKS, 256, 0, stream>>>(dstL, payL, tail, offsets, cursor, bucket,
                                                    cap, SLICED_STRIDE);

    node_init_kernel<<<(N * 32 + 255) / 256, 256, 0, stream>>>(x, z, atom_emb, z_emb, hb, N);
    comb_kernel<<<dim3((216 * D + 255) / 256, 2), 256, 0, stream>>>(bond_emb, comb);
    pack_w_kernel<<<dim3((D * 2 * D + 255) / 256, 2), 256, 0, stream>>>(W1, w1p, D * 2 * D, 8);
    pack_w_kernel<<<dim3((2 * D * D + 255) / 256, 2), 256, 0, stream>>>(W2, w2p, 2 * D * D, 7);

    for (int l = 0; l < 2; ++l) {
        gather_reduce_kernel<<<(N * 16 + 255) / 256, 256, 0, stream>>>(
            offsets, bucket, comb + (size_t)l * 216 * D, hb, eps + l, pre_bf, N);

        mfma_gemm_kernel<128, 256, 0, 1><<<ngb, 256, 0, stream>>>(
            pre_bf, w1p + (size_t)l * D * 2 * D, b1 + (size_t)l * 2 * D,
            nullptr, nullptr, out1_bf, nullptr, partial1, N);
        reduce_stats_kernel<256><<<256, 256, 0, stream>>>(
            partial1, ngb, g1 + (size_t)l * 2 * D, be1 + (size_t)l * 2 * D,
            scale1, shift1, invN);

        mfma_gemm_kernel<256, 128, 1, 0><<<ngb, 256, 0, stream>>>(
            out1_bf, w2p + (size_t)l * 2 * D * D, b2 + (size_t)l * D,
            scale1, shift1, nullptr, out2, partial2, N);
        reduce_stats_kernel<128><<<128, 256, 0, stream>>>(
            partial2, ngb, bng + (size_t)l * D, bnb + (size_t)l * D,
            scale2, shift2, invN);

        bn_apply_kernel<<<(N * 32 + 255) / 256, 256, 0, stream>>>(out2, h, hb, scale2, shift2,
                                                                  N, l == 0 ? 0 : 1);
    }
}

// Round 8
// 578.441 us; speedup vs baseline: 1.2844x; 1.1755x over previous
//
#include <hip/hip_runtime.h>

#define D 128
#define BN_EPS 1e-5f
#define NSUB 1024
#define CAP2 2048

typedef __attribute__((ext_vector_type(8))) short short8;   // 8 x bf16 (4 VGPRs)
typedef __attribute__((ext_vector_type(4))) float floatx4;  // MFMA accumulator

__device__ __forceinline__ float bf2f(unsigned short u) {
    unsigned int x = ((unsigned int)u) << 16;
    return __builtin_bit_cast(float, x);
}
__device__ __forceinline__ unsigned short f2bf(float f) {
    unsigned int x = __builtin_bit_cast(unsigned int, f);
    x = x + 0x7FFFu + ((x >> 16) & 1u);  // round-to-nearest-even
    return (unsigned short)(x >> 16);
}

// ---------------------------------------------------------------------------
// hb0 = bf16( sum_f atom_emb[f, x[n,f], :] + z_emb[z[n], :] )
__global__ void node_init_kernel(const int* __restrict__ x, const int* __restrict__ z,
                                 const float* __restrict__ atom_emb,
                                 const float* __restrict__ z_emb,
                                 unsigned short* __restrict__ hb, int N) {
    int gid = blockIdx.x * blockDim.x + threadIdx.x;
    int node = gid >> 5;
    if (node >= N) return;
    int d0 = (gid & 31) * 4;
    float4 acc = *(const float4*)(z_emb + (size_t)z[node] * D + d0);
#pragma unroll
    for (int f = 0; f < 9; ++f) {
        int v = x[node * 9 + f];
        const float4 t = *(const float4*)(atom_emb + (size_t)(f * 119 + v) * D + d0);
        acc.x += t.x; acc.y += t.y; acc.z += t.z; acc.w += t.w;
    }
    ushort4 o;
    o.x = f2bf(acc.x); o.y = f2bf(acc.y); o.z = f2bf(acc.z); o.w = f2bf(acc.w);
    *(ushort4*)(hb + (size_t)node * D + d0) = o;
}

// ---------------------------------------------------------------------------
// Level-1 partition: edges -> 8 per-dst-slice int2{dst, pay} lists.
// pay = src | comb_idx<<17 (25 bits).
__global__ __launch_bounds__(256)
void partition1_kernel(const int* __restrict__ ei, const int* __restrict__ ea,
                       int2* __restrict__ l1, int* __restrict__ tail1,
                       int E, int N, int capE, int ntiles, int nblocks) {
    __shared__ int lcnt[8], lbase[8];
    const int tid = threadIdx.x;
    for (int tile = blockIdx.x; tile < ntiles; tile += nblocks) {
        const int tb = tile * 4096;
        if (tid < 8) lcnt[tid] = 0;
        __syncthreads();
        int mydst[16], mypay[16];
#pragma unroll
        for (int j = 0; j < 16; ++j) {
            int e = tb + j * 256 + tid;
            if (e < E) {
                int dst = ei[E + e];
                int c = (ea[3 * e] * 6 + ea[3 * e + 1]) * 6 + ea[3 * e + 2];
                mydst[j] = dst;
                mypay[j] = ei[e] | (c << 17);
                atomicAdd(&lcnt[(int)((8LL * dst) / N)], 1);
            } else {
                mydst[j] = -1;
            }
        }
        __syncthreads();
        if (tid < 8) {
            lbase[tid] = atomicAdd(&tail1[tid], lcnt[tid]);
            lcnt[tid] = 0;
        }
        __syncthreads();
#pragma unroll
        for (int j = 0; j < 16; ++j) {
            if (mydst[j] >= 0) {
                int s = (int)((8LL * mydst[j]) / N);
                int pos = lbase[s] + atomicAdd(&lcnt[s], 1);
                if (pos < capE) l1[(size_t)s * capE + pos] = make_int2(mydst[j], mypay[j]);
            }
        }
        __syncthreads();
    }
}

// ---------------------------------------------------------------------------
// Level-2 partition: slice list -> 128 sub-slice lists (4 B packed entries:
// pay | local_dst<<25). Sub-slice k covers nodes [ceil(kN/1024), ceil((k+1)N/1024)).
__global__ __launch_bounds__(256)
void partition2_kernel(const int2* __restrict__ l1, const int* __restrict__ tail1,
                       unsigned int* __restrict__ subL, int* __restrict__ tail2,
                       int N, int capE, int G) {
    __shared__ int lcnt[128], lbase[128];
    const int s = blockIdx.x & 7;
    const int g = blockIdx.x >> 3;
    const int tid = threadIdx.x;
    const int len = min(tail1[s], capE);
    const int2* src = l1 + (size_t)s * capE;
    for (int tb = g * 4096; tb < len; tb += G * 4096) {
        if (tid < 128) lcnt[tid] = 0;
        __syncthreads();
        int2 e[16];
        int sub[16];
#pragma unroll
        for (int j = 0; j < 16; ++j) {
            int i = tb + j * 256 + tid;
            if (i < len) {
                e[j] = src[i];
                sub[j] = (int)((1024LL * e[j].x) / N) - (s << 7);
                atomicAdd(&lcnt[sub[j]], 1);
            } else {
                sub[j] = -1;
            }
        }
        __syncthreads();
        if (tid < 128) {
            lbase[tid] = atomicAdd(&tail2[(s << 7) + tid], lcnt[tid]);
            lcnt[tid] = 0;
        }
        __syncthreads();
#pragma unroll
        for (int j = 0; j < 16; ++j) {
            if (sub[j] >= 0) {
                int k = (s << 7) + sub[j];
                int lo = (int)(((long long)k * N + 1023) >> 10);
                int pos = lbase[sub[j]] + atomicAdd(&lcnt[sub[j]], 1);
                if (pos < CAP2)
                    subL[(size_t)k * CAP2 + pos] =
                        (unsigned int)e[j].y | ((unsigned int)(e[j].x - lo) << 25);
            }
        }
        __syncthreads();
    }
}

// ---------------------------------------------------------------------------
// Exclusive scan of 1024 sub-slice tails -> subbase; offsets[N] = E.
__global__ __launch_bounds__(1024)
void subscan_kernel(const int* __restrict__ tail2, int* __restrict__ subbase,
                    int* __restrict__ offsets, int N) {
    const int tid = threadIdx.x, lane = tid & 63, wid = tid >> 6;
    int v = min(tail2[tid], CAP2);
    int s = v;
#pragma unroll
    for (int off = 1; off < 64; off <<= 1) {
        int t = __shfl_up(s, off, 64);
        if (lane >= off) s += t;
    }
    __shared__ int ws[16];
    if (lane == 63) ws[wid] = s;
    __syncthreads();
    if (wid == 0) {
        int w = (lane < 16) ? ws[lane] : 0;
#pragma unroll
        for (int off = 1; off < 16; off <<= 1) {
            int t = __shfl_up(w, off, 64);
            if (lane >= off) w += t;
        }
        if (lane < 16) ws[lane] = w;
    }
    __syncthreads();
    int excl = (wid ? ws[wid - 1] : 0) + s - v;
    subbase[tid] = excl;
    if (tid == 1023) offsets[N] = excl + v;
}

// ---------------------------------------------------------------------------
// One block per sub-slice: LDS counting sort -> contiguous coalesced writes of
// bucket + offsets. No global scatter, no global cursor atomics.
__global__ __launch_bounds__(256)
void csr_sort_kernel(const unsigned int* __restrict__ subL, const int* __restrict__ tail2,
                     const int* __restrict__ subbase, int* __restrict__ offsets,
                     int* __restrict__ bucket, int N) {
    const int k = blockIdx.x;
    const int tid = threadIdx.x, lane = tid & 63, wid = tid >> 6;
    const int len = min(tail2[k], CAP2);
    const int base = subbase[k];
    const int lo = (int)(((long long)k * N + 1023) >> 10);
    const int hi = (int)(((long long)(k + 1) * N + 1023) >> 10);
    const int nn = hi - lo;  // <= 128
    __shared__ int cnt[128], loff[128], wsum[4];
    __shared__ unsigned int sorted[CAP2];
    const unsigned int* src = subL + (size_t)k * CAP2;

    if (tid < 128) cnt[tid] = 0;
    __syncthreads();
    for (int i = tid; i < len; i += 256) atomicAdd(&cnt[src[i] >> 25], 1);
    __syncthreads();
    // exclusive scan of cnt[0..127] (first 2 waves meaningful)
    int v = (tid < 128) ? cnt[tid] : 0;
    int s = v;
#pragma unroll
    for (int off = 1; off < 64; off <<= 1) {
        int t = __shfl_up(s, off, 64);
        if (lane >= off) s += t;
    }
    if (lane == 63) wsum[wid] = s;
    __syncthreads();
    if (tid < 128) loff[tid] = ((wid == 1) ? wsum[0] : 0) + s - v;
    __syncthreads();
    if (tid < nn) offsets[lo + tid] = base + loff[tid];
    if (tid < 128) cnt[tid] = 0;
    __syncthreads();
    for (int i = tid; i < len; i += 256) {
        unsigned int e = src[i];
        int ld = e >> 25;
        int pos = loff[ld] + atomicAdd(&cnt[ld], 1);
        sorted[pos] = e & 0x1FFFFFFu;
    }
    __syncthreads();
    for (int i = tid; i < len; i += 256) bucket[base + i] = (int)sorted[i];
}

// ---------------------------------------------------------------------------
// comb[layer][c][d] = bf16( b0[a0][d] + b1[a1][d] + b2[a2][d] )
__global__ void comb_kernel(const float* __restrict__ bond_emb, unsigned short* __restrict__ comb) {
    int idx = blockIdx.x * 256 + threadIdx.x;  // c*128 + d
    if (idx >= 216 * D) return;
    int c = idx >> 7, d = idx & 127;
    int a0 = c / 36, a1 = (c / 6) % 6, a2 = c % 6;
    const float* b = bond_emb + (size_t)blockIdx.y * 3 * 6 * D;
    float v = b[(0 * 6 + a0) * D + d] + b[(1 * 6 + a1) * D + d] + b[(2 * 6 + a2) * D + d];
    comb[(size_t)blockIdx.y * 216 * D + idx] = f2bf(v);
}

// ---------------------------------------------------------------------------
// Pack W [K][NCOLS] fp32 row-major -> FRAGMENT-LINEAR order (see R7 notes).
__global__ void pack_w_kernel(const float* __restrict__ W, unsigned short* __restrict__ Wp,
                              int total, int logN) {
    int idx = blockIdx.x * 256 + threadIdx.x;
    if (idx >= total) return;
    int NCOLS = 1 << logN;
    int k = idx >> logN, n = idx & (NCOLS - 1);
    int k0 = k >> 5, kq = k & 31, q = kq >> 3, j = kq & 7;
    int t = n >> 4, ln = n & 15;
    size_t dest = (((size_t)k0 * (NCOLS >> 4) + t) << 9) + ((q << 4) + ln) * 8 + j;
    const float* Wl = W + (size_t)blockIdx.y * total;
    unsigned short* Wpl = Wp + (size_t)blockIdx.y * total;
    Wpl[dest] = f2bf(Wl[idx]);
}

// ---------------------------------------------------------------------------
// pre[n] = bf16( (1+eps)*h[n] + sum_{e in in(n)} relu(h[src_e] + comb[c_e]) )
__global__ __launch_bounds__(256)
void gather_reduce_kernel(const int* __restrict__ offsets, const int* __restrict__ bucket,
                          const unsigned short* __restrict__ comb,
                          const unsigned short* __restrict__ hb,
                          const float* __restrict__ eps_l,
                          unsigned short* __restrict__ pre, int N) {
    int gid = blockIdx.x * blockDim.x + threadIdx.x;
    int node = gid >> 4;
    if (node >= N) return;
    int d0 = (gid & 15) * 8;

    union U8 { int4 i; unsigned short u[8]; };
    float s = 1.0f + eps_l[0];
    float a[8];
    {
        U8 hv; hv.i = *(const int4*)(hb + (size_t)node * D + d0);
#pragma unroll
        for (int j = 0; j < 8; ++j) a[j] = bf2f(hv.u[j]) * s;
    }
    const int beg = offsets[node], end = offsets[node + 1];
    for (int p = beg; p < end; p += 4) {
        int rem = end - p;
        int pk0 = bucket[p];
        int pk1 = bucket[rem > 1 ? p + 1 : p];
        int pk2 = bucket[rem > 2 ? p + 2 : p];
        int pk3 = bucket[rem > 3 ? p + 3 : p];
        U8 h0, h1, h2, h3, c0, c1, c2, c3;
        h0.i = *(const int4*)(hb + (size_t)(pk0 & 0x1FFFF) * D + d0);
        c0.i = *(const int4*)(comb + (size_t)((pk0 >> 17) & 0xFF) * D + d0);
        h1.i = *(const int4*)(hb + (size_t)(pk1 & 0x1FFFF) * D + d0);
        c1.i = *(const int4*)(comb + (size_t)((pk1 >> 17) & 0xFF) * D + d0);
        h2.i = *(const int4*)(hb + (size_t)(pk2 & 0x1FFFF) * D + d0);
        c2.i = *(const int4*)(comb + (size_t)((pk2 >> 17) & 0xFF) * D + d0);
        h3.i = *(const int4*)(hb + (size_t)(pk3 & 0x1FFFF) * D + d0);
        c3.i = *(const int4*)(comb + (size_t)((pk3 >> 17) & 0xFF) * D + d0);
#pragma unroll
        for (int j = 0; j < 8; ++j) a[j] += fmaxf(bf2f(h0.u[j]) + bf2f(c0.u[j]), 0.0f);
        if (rem > 1) {
#pragma unroll
            for (int j = 0; j < 8; ++j) a[j] += fmaxf(bf2f(h1.u[j]) + bf2f(c1.u[j]), 0.0f);
        }
        if (rem > 2) {
#pragma unroll
            for (int j = 0; j < 8; ++j) a[j] += fmaxf(bf2f(h2.u[j]) + bf2f(c2.u[j]), 0.0f);
        }
        if (rem > 3) {
#pragma unroll
            for (int j = 0; j < 8; ++j) a[j] += fmaxf(bf2f(h3.u[j]) + bf2f(c3.u[j]), 0.0f);
        }
    }
    U8 o;
#pragma unroll
    for (int j = 0; j < 8; ++j) o.u[j] = f2bf(a[j]);
    *(int4*)(pre + (size_t)node * D + d0) = o.i;
}

// ---------------------------------------------------------------------------
// MFMA GEMM, B staged in LDS (2 x 32KB phases), A prefetched; fused stats.
template <int K, int NCOLS, int TRANSFORM, int OUTBF>
__global__ __launch_bounds__(256)
void mfma_gemm_kernel(const unsigned short* __restrict__ A,
                      const unsigned short* __restrict__ Wp,
                      const float* __restrict__ bias,
                      const float* __restrict__ tscale, const float* __restrict__ tshift,
                      unsigned short* __restrict__ Cbf, float* __restrict__ Cf,
                      float* __restrict__ partial, int M) {
    constexpr int NT = NCOLS / 16;
    constexpr int NCHUNK = K / 32;
    constexpr int CPP = NCHUNK / 2;
    __shared__ unsigned short Ws[16384];
    __shared__ float red[NCOLS * 2];

    const int tid = threadIdx.x;
    const int wave = tid >> 6, lane = tid & 63;
    const int quad = lane >> 4, ln = lane & 15;
    const int m_base = blockIdx.x * 64 + wave * 16;
    int arow = m_base + ln;
    if (arow >= M) arow = M - 1;
    const int kq = quad * 8;

    int4 araw[NCHUNK];
#pragma unroll
    for (int c = 0; c < NCHUNK; ++c)
        araw[c] = *(const int4*)(A + (size_t)arow * K + c * 32 + kq);

    for (int i = tid; i < NCOLS * 2; i += 256) red[i] = 0.f;

    floatx4 acc[NT];
#pragma unroll
    for (int t = 0; t < NT; ++t) acc[t] = (floatx4){0.f, 0.f, 0.f, 0.f};

#pragma unroll
    for (int ph = 0; ph < 2; ++ph) {
        if (ph) __syncthreads();
#pragma unroll
        for (int i = 0; i < 16384; i += 2048)
            *(int4*)&Ws[i + tid * 8] = *(const int4*)&Wp[ph * 16384 + i + tid * 8];
        __syncthreads();
#pragma unroll
        for (int cc = 0; cc < CPP; ++cc) {
            const int c = ph * CPP + cc;
            short8 afrag;
            if constexpr (TRANSFORM) {
                union { int4 i; unsigned short u[8]; } raw;
                raw.i = araw[c];
                const int kb = c * 32 + kq;
                float4 sc0 = *(const float4*)(tscale + kb);
                float4 sc1 = *(const float4*)(tscale + kb + 4);
                float4 sh0 = *(const float4*)(tshift + kb);
                float4 sh1 = *(const float4*)(tshift + kb + 4);
                union { short8 v; unsigned short u[8]; } au;
                au.u[0] = f2bf(fmaxf(bf2f(raw.u[0]) * sc0.x + sh0.x, 0.f));
                au.u[1] = f2bf(fmaxf(bf2f(raw.u[1]) * sc0.y + sh0.y, 0.f));
                au.u[2] = f2bf(fmaxf(bf2f(raw.u[2]) * sc0.z + sh0.z, 0.f));
                au.u[3] = f2bf(fmaxf(bf2f(raw.u[3]) * sc0.w + sh0.w, 0.f));
                au.u[4] = f2bf(fmaxf(bf2f(raw.u[4]) * sc1.x + sh1.x, 0.f));
                au.u[5] = f2bf(fmaxf(bf2f(raw.u[5]) * sc1.y + sh1.y, 0.f));
                au.u[6] = f2bf(fmaxf(bf2f(raw.u[6]) * sc1.z + sh1.z, 0.f));
                au.u[7] = f2bf(fmaxf(bf2f(raw.u[7]) * sc1.w + sh1.w, 0.f));
                afrag = au.v;
            } else {
                afrag = __builtin_bit_cast(short8, araw[c]);
            }
#pragma unroll
            for (int t = 0; t < NT; ++t) {
                short8 bfrag = *(const short8*)&Ws[(((cc * NT) + t) << 9) + lane * 8];
                acc[t] = __builtin_amdgcn_mfma_f32_16x16x32_bf16(afrag, bfrag, acc[t], 0, 0, 0);
            }
        }
    }

#pragma unroll
    for (int t = 0; t < NT; ++t) {
        int col = t * 16 + ln;
        float bv = bias[col];
        float sv = 0.f, qv = 0.f;
#pragma unroll
        for (int r = 0; r < 4; ++r) {
            int row = m_base + quad * 4 + r;
            if (row < M) {
                float v = acc[t][r] + bv;
                sv += v; qv += v * v;
                if constexpr (OUTBF) Cbf[(size_t)row * NCOLS + col] = f2bf(v);
                else                 Cf[(size_t)row * NCOLS + col] = v;
            }
        }
        sv += __shfl_xor(sv, 16, 64); sv += __shfl_xor(sv, 32, 64);
        qv += __shfl_xor(qv, 16, 64); qv += __shfl_xor(qv, 32, 64);
        if (quad == 0) {
            atomicAdd(&red[col], sv);
            atomicAdd(&red[NCOLS + col], qv);
        }
    }
    __syncthreads();
    float* pout = partial + (size_t)blockIdx.x * (NCOLS * 2);
    for (int i = tid; i < NCOLS * 2; i += 256) pout[i] = red[i];
}

// ---------------------------------------------------------------------------
template <int NCOLS>
__global__ __launch_bounds__(256)
void reduce_stats_kernel(const float* __restrict__ partial, int nb,
                         const float* __restrict__ g, const float* __restrict__ b,
                         float* __restrict__ scale, float* __restrict__ shift, float invN) {
    const int col = blockIdx.x;
    const int tid = threadIdx.x;
    float s = 0.f, q = 0.f;
    for (int bb = tid; bb < nb; bb += 256) {
        const float* p = partial + (size_t)bb * (NCOLS * 2);
        s += p[col];
        q += p[NCOLS + col];
    }
#pragma unroll
    for (int off = 32; off > 0; off >>= 1) {
        s += __shfl_xor(s, off, 64);
        q += __shfl_xor(q, off, 64);
    }
    __shared__ float ws[4], wq[4];
    if ((tid & 63) == 0) { ws[tid >> 6] = s; wq[tid >> 6] = q; }
    __syncthreads();
    if (tid == 0) {
        s = ws[0] + ws[1] + ws[2] + ws[3];
        q = wq[0] + wq[1] + wq[2] + wq[3];
        float mean = s * invN;
        float var = q * invN - mean * mean;
        float inv = 1.0f / sqrtf(var + BN_EPS);
        float sc = g[col] * inv;
        scale[col] = sc;
        shift[col] = b[col] - mean * sc;
    }
}

// ---------------------------------------------------------------------------
// mode 0: hb = bf16(relu(bn(out2)))   mode 1: h = bn(out2) fp32 (final)
__global__ void bn_apply_kernel(const float* __restrict__ X, float* __restrict__ Yf,
                                unsigned short* __restrict__ Yb,
                                const float* __restrict__ scale, const float* __restrict__ shift,
                                int N, int mode) {
    int gid = blockIdx.x * blockDim.x + threadIdx.x;
    int node = gid >> 5;
    if (node >= N) return;
    int d0 = (gid & 31) * 4;
    float4 v = *(const float4*)(X + (size_t)node * D + d0);
    float4 sc = *(const float4*)(scale + d0);
    float4 sh = *(const float4*)(shift + d0);
    float4 o;
    o.x = v.x * sc.x + sh.x;
    o.y = v.y * sc.y + sh.y;
    o.z = v.z * sc.z + sh.z;
    o.w = v.w * sc.w + sh.w;
    if (mode == 0) {
        ushort4 ob;
        ob.x = f2bf(fmaxf(o.x, 0.f));
        ob.y = f2bf(fmaxf(o.y, 0.f));
        ob.z = f2bf(fmaxf(o.z, 0.f));
        ob.w = f2bf(fmaxf(o.w, 0.f));
        *(ushort4*)(Yb + (size_t)node * D + d0) = ob;
    } else {
        *(float4*)(Yf + (size_t)node * D + d0) = o;
    }
}

// ---------------------------------------------------------------------------
extern "C" void kernel_launch(void* const* d_in, const int* in_sizes, int n_in,
                              void* d_out, int out_size, void* d_ws, size_t ws_size,
                              hipStream_t stream) {
    const int*   x        = (const int*)d_in[0];
    const int*   z        = (const int*)d_in[1];
    const int*   ei       = (const int*)d_in[2];
    const int*   ea       = (const int*)d_in[3];
    const float* atom_emb = (const float*)d_in[4];
    const float* z_emb    = (const float*)d_in[5];
    const float* bond_emb = (const float*)d_in[6];
    const float* eps      = (const float*)d_in[7];
    const float* W1       = (const float*)d_in[8];
    const float* b1       = (const float*)d_in[9];
    const float* g1       = (const float*)d_in[10];
    const float* be1      = (const float*)d_in[11];
    const float* W2       = (const float*)d_in[12];
    const float* b2       = (const float*)d_in[13];
    const float* bng      = (const float*)d_in[14];
    const float* bnb      = (const float*)d_in[15];

    const int N = in_sizes[1];
    const int E = in_sizes[3] / 3;

    float* h = (float*)d_out;  // final [N,128] fp32

    const int ngb = (N + 63) / 64;   // GEMM grid
    const int capE = E / 8 + E / 64; // per-slice L1 list capacity (~60 sigma)

    char* ws = (char*)d_ws;
    size_t off = 0;
    auto alloc = [&](size_t bytes) { void* p = ws + off; off += (bytes + 255) & ~(size_t)255; return p; };
    unsigned short* pre_bf = (unsigned short*)alloc((size_t)N * D * 2);      // 25.6 MB
    unsigned short* extra  = (unsigned short*)alloc((size_t)N * D * 2);      // 25.6 MB (out2 tail)
    (void)extra;
    float* out2 = (float*)pre_bf;                                            // spans pre_bf+extra
    unsigned short* out1_bf = (unsigned short*)alloc((size_t)N * 2 * D * 2); // 51.2 MB
    unsigned short* hb      = (unsigned short*)alloc((size_t)N * D * 2);     // 25.6 MB
    int* offsets = (int*)alloc((size_t)(N + 1) * 4);
    int* bucket  = (int*)alloc((size_t)E * 4);
    int2* l1     = (int2*)alloc((size_t)8 * capE * 8);           // ~14.4 MB
    unsigned int* subL = (unsigned int*)alloc((size_t)NSUB * CAP2 * 4); // 8 MB
    int* subbase = (int*)alloc(NSUB * 4);
    float* stats = (float*)alloc(1024 * 4);
    float* partial1 = (float*)alloc((size_t)ngb * 512 * 4);  // 3.2 MB
    float* partial2 = (float*)alloc((size_t)ngb * 256 * 4);  // 1.6 MB
    unsigned short* w1p  = (unsigned short*)alloc((size_t)2 * D * 2 * D * 2);
    unsigned short* w2p  = (unsigned short*)alloc((size_t)2 * 2 * D * D * 2);
    unsigned short* comb = (unsigned short*)alloc((size_t)2 * 216 * D * 2);
    // transient tails alias out1_bf (dead until first GEMM1 write)
    int* tail1 = (int*)out1_bf;   // 8 ints
    int* tail2 = tail1 + 8;       // 1024 ints

    float* scale1 = stats;          // 256
    float* shift1 = stats + 256;    // 256
    float* scale2 = stats + 512;    // 128
    float* shift2 = stats + 640;    // 128

    const float invN = 1.0f / (float)N;
    const int ntiles = (E + 4095) / 4096;

    // --- CSR build: partition1 -> partition2 -> subscan -> LDS counting sort ---
    hipMemsetAsync(tail1, 0, (8 + NSUB) * sizeof(int), stream);
    partition1_kernel<<<256, 256, 0, stream>>>(ei, ea, l1, tail1, E, N, capE, ntiles, 256);
    partition2_kernel<<<256, 256, 0, stream>>>(l1, tail1, subL, tail2, N, capE, 32);
    subscan_kernel<<<1, 1024, 0, stream>>>(tail2, subbase, offsets, N);
    csr_sort_kernel<<<NSUB, 256, 0, stream>>>(subL, tail2, subbase, offsets, bucket, N);

    node_init_kernel<<<(N * 32 + 255) / 256, 256, 0, stream>>>(x, z, atom_emb, z_emb, hb, N);
    comb_kernel<<<dim3((216 * D + 255) / 256, 2), 256, 0, stream>>>(bond_emb, comb);
    pack_w_kernel<<<dim3((D * 2 * D + 255) / 256, 2), 256, 0, stream>>>(W1, w1p, D * 2 * D, 8);
    pack_w_kernel<<<dim3((2 * D * D + 255) / 256, 2), 256, 0, stream>>>(W2, w2p, 2 * D * D, 7);

    for (int l = 0; l < 2; ++l) {
        gather_reduce_kernel<<<(N * 16 + 255) / 256, 256, 0, stream>>>(
            offsets, bucket, comb + (size_t)l * 216 * D, hb, eps + l, pre_bf, N);

        mfma_gemm_kernel<128, 256, 0, 1><<<ngb, 256, 0, stream>>>(
            pre_bf, w1p + (size_t)l * D * 2 * D, b1 + (size_t)l * 2 * D,
            nullptr, nullptr, out1_bf, nullptr, partial1, N);
        reduce_stats_kernel<256><<<256, 256, 0, stream>>>(
            partial1, ngb, g1 + (size_t)l * 2 * D, be1 + (size_t)l * 2 * D,
            scale1, shift1, invN);

        mfma_gemm_kernel<256, 128, 1, 0><<<ngb, 256, 0, stream>>>(
            out1_bf, w2p + (size_t)l * 2 * D * D, b2 + (size_t)l * D,
            scale1, shift1, nullptr, out2, partial2, N);
        reduce_stats_kernel<128><<<128, 256, 0, stream>>>(
            partial2, ngb, bng + (size_t)l * D, bnb + (size_t)l * D,
            scale2, shift2, invN);

        bn_apply_kernel<<<(N * 32 + 255) / 256, 256, 0, stream>>>(out2, h, hb, scale2, shift2,
                                                                  N, l == 0 ? 0 : 1);
    }
}